// Round 4
// baseline (537.043 us; speedup 1.0000x reference)
//
#include <hip/hip_runtime.h>

#define S_LEN 2048
#define HID   1152
#define HEADS 16
#define HD    72
#define ROT   36
#define LD3   3456   // 3*HID
#define FF    4304
#define FFP   4320   // FF padded to mult of 32

typedef short s16x8 __attribute__((ext_vector_type(8)));
typedef short s16x4 __attribute__((ext_vector_type(4)));
typedef float f32x4 __attribute__((ext_vector_type(4)));
typedef short bf_t;  // bf16 bit pattern

__device__ __forceinline__ short f2b(float f) {
  unsigned u = __float_as_uint(f);
  u += 0x7fffu + ((u >> 16) & 1u);   // RNE
  return (short)(u >> 16);
}
__device__ __forceinline__ float b2f(short h) {
  return __uint_as_float(((unsigned)(unsigned short)h) << 16);
}
__device__ __forceinline__ float gelu_f(float x) {
  float t = tanhf(0.7978845608028654f * (x + 0.044715f * x * x * x));
  return 0.5f * x * (1.0f + t);
}

typedef const __attribute__((address_space(1))) void* gas_p;
typedef __attribute__((address_space(3))) void* las_p;
__device__ __forceinline__ void gload16(const void* g, void* l) {
  __builtin_amdgcn_global_load_lds((gas_p)g, (las_p)l, 16, 0, 0);
}

// ---------------- weight convert f32 -> bf16, vectorized x4, k-zero-pad ------
__global__ __launch_bounds__(256) void convw4_kernel(
    const float* __restrict__ src, int N, int K,
    bf_t* __restrict__ dst, int Kpad)
{
  int idx = blockIdx.x * 256 + threadIdx.x;
  int kq = Kpad >> 2;
  if (idx >= N * kq) return;
  int n = idx / kq, k = (idx % kq) << 2;
  s16x4 o;
  if (k + 3 < K) {
    float4 v = *(const float4*)(src + (size_t)n * K + k);
    o[0] = f2b(v.x); o[1] = f2b(v.y); o[2] = f2b(v.z); o[3] = f2b(v.w);
  } else {
#pragma unroll
    for (int j = 0; j < 4; j++) {
      int kk = k + j;
      o[j] = (kk < K) ? f2b(src[(size_t)n * K + kk]) : (short)0;
    }
  }
  *(s16x4*)(dst + (size_t)n * Kpad + k) = o;
}

// ---------------- cos/sin table ----------------
__global__ __launch_bounds__(256) void costab_kernel(
    const float* __restrict__ rot, float* __restrict__ ct, float* __restrict__ st)
{
  int i = blockIdx.x * 256 + threadIdx.x;
  if (i < S_LEN * ROT) { float f = rot[i]; ct[i] = cosf(f); st[i] = sinf(f); }
}

// ---------------- layernorm: f32 in -> bf16 out ----------------
__global__ __launch_bounds__(256) void ln_kernel(
    const float* __restrict__ x, const float* __restrict__ wgt,
    const float* __restrict__ bia, bf_t* __restrict__ outb)
{
  const int row = blockIdx.x, tid = threadIdx.x;
  const float4* xr = (const float4*)(x + (size_t)row * HID);
  float4 a = xr[tid];
  float4 b2 = make_float4(0.f, 0.f, 0.f, 0.f);
  const bool has2 = tid < 32;
  if (has2) b2 = xr[256 + tid];
  float s = a.x + a.y + a.z + a.w + b2.x + b2.y + b2.z + b2.w;
  float q = a.x*a.x + a.y*a.y + a.z*a.z + a.w*a.w
          + b2.x*b2.x + b2.y*b2.y + b2.z*b2.z + b2.w*b2.w;
  for (int mk = 32; mk; mk >>= 1) { s += __shfl_xor(s, mk); q += __shfl_xor(q, mk); }
  __shared__ float red[16];
  if ((tid & 63) == 0) { red[tid >> 6] = s; red[8 + (tid >> 6)] = q; }
  __syncthreads();
  if (tid == 0) {
    red[4]  = red[0] + red[1] + red[2] + red[3];
    red[12] = red[8] + red[9] + red[10] + red[11];
  }
  __syncthreads();
  float mean = red[4] * (1.0f / HID);
  float var  = red[12] * (1.0f / HID) - mean * mean;
  float rstd = rsqrtf(var + 1e-6f);
  const float4* w4 = (const float4*)wgt;
  const float4* b4 = (const float4*)bia;
  s16x4* o4 = (s16x4*)(outb + (size_t)row * HID);
  {
    float4 wv = w4[tid], bv = b4[tid];
    s16x4 o;
    o[0] = f2b((a.x - mean) * rstd * wv.x + bv.x);
    o[1] = f2b((a.y - mean) * rstd * wv.y + bv.y);
    o[2] = f2b((a.z - mean) * rstd * wv.z + bv.z);
    o[3] = f2b((a.w - mean) * rstd * wv.w + bv.w);
    o4[tid] = o;
  }
  if (has2) {
    float4 wv = w4[256 + tid], bv = b4[256 + tid];
    s16x4 o;
    o[0] = f2b((b2.x - mean) * rstd * wv.x + bv.x);
    o[1] = f2b((b2.y - mean) * rstd * wv.y + bv.y);
    o[2] = f2b((b2.z - mean) * rstd * wv.z + bv.z);
    o[3] = f2b((b2.w - mean) * rstd * wv.w + bv.w);
    o4[256 + tid] = o;
  }
}

// ---------------- rotary in-place on qkv (bf16), q pre-scaled ----------------
__global__ __launch_bounds__(256) void rotary_kernel(
    bf_t* __restrict__ qkv, const float* __restrict__ ct, const float* __restrict__ st)
{
  int idx = blockIdx.x * 256 + threadIdx.x;
  if (idx >= S_LEN * HEADS * ROT) return;
  int t = idx / (HEADS * ROT);
  int r = idx % (HEADS * ROT);
  int h = r / ROT, dd = r % ROT;
  float c = ct[t * ROT + dd], s = st[t * ROT + dd];
  size_t base = (size_t)t * LD3 + h * HD + dd;
  float q1 = b2f(qkv[base]),        q2 = b2f(qkv[base + ROT]);
  float k1 = b2f(qkv[base + HID]),  k2 = b2f(qkv[base + HID + ROT]);
  const float scale = 0.11785113019775793f; // 1/sqrt(72)
  qkv[base]             = f2b((q1 * c - q2 * s) * scale);
  qkv[base + ROT]       = f2b((q2 * c + q1 * s) * scale);
  qkv[base + HID]       = f2b(k1 * c - k2 * s);
  qkv[base + HID + ROT] = f2b(k2 * c + k1 * s);
}

// ---------------- GEMM: C[M,N] = A[M,K] * B[N,K]^T --------------------------
// BM=128, BN=64, BK=32, 4 waves (2x2). T3+T4: 3 LDS buffers, depth-2 prefetch,
// counted vmcnt(3) (never 0 in steady state), ONE barrier per K-step.
// Hazards: RAW ok (vmcnt->barrier before ds_read); WAR ok (STAGE(t+2) hits
// buf[(t-1)%3] whose readers drained lgkm before prior loop-back + barrier).
// MODE 0: out bf16 = acc + bias
// MODE 2: out bf16 = gelu(acc + bias) for cc<nvalid; 0 for nvalid<=cc<ldc
// MODE 3: out f32 partial = acc, at part + bz*S_LEN*ldc (split-K)
template<int MODE>
__global__ __launch_bounds__(256, 4) void gemm_bt(
    const bf_t* __restrict__ A, int lda,
    const bf_t* __restrict__ B, int ldb,
    const float* __restrict__ bias, int nbias,
    void* outp, int ldc, int nvalid, int K, int kchunk)
{
  __shared__ __align__(16) bf_t As[3][128 * 32];
  __shared__ __align__(16) bf_t Bs[3][64 * 32];
  const int tid = threadIdx.x;
  const int l = tid & 63, w = tid >> 6;
  const int lr = l & 15, lg = l >> 4;
  const int wm = (w >> 1) * 64, wn = (w & 1) * 32;

  // bijective XCD-aware swizzle over flattened grid (all grids are %8==0)
  unsigned gx = gridDim.x, gy = gridDim.y, gz = gridDim.z;
  unsigned nwg = gx * gy * gz;
  unsigned lin = (blockIdx.z * gy + blockIdx.y) * gx + blockIdx.x;
  if ((nwg & 7u) == 0u) {
    unsigned q = nwg >> 3;
    lin = (lin & 7u) * q + (lin >> 3);
  }
  const unsigned bz = lin / (gx * gy);
  const unsigned rem = lin % (gx * gy);
  const unsigned by = rem / gx, bx = rem % gx;

  const int rowA0 = by * 128, colB0 = bx * 64;
  const int kb0 = bz * kchunk;
  int kb1 = kb0 + kchunk; if (kb1 > K) kb1 = K;
  const int nt = (kb1 - kb0) >> 5;          // kchunk always a multiple of 32

  // staging offsets: A tile 128x32 (8 KB, 2 loads/thread), B tile 64x32 (4 KB, 1)
  const int oA1 = tid * 16, oA2 = oA1 + 4096;
  const int rA1 = oA1 >> 6, cA1 = oA1 & 63;
  const int rA2 = rA1 + 64;
  const int oB = tid * 16;
  const int rB = oB >> 6, cB = oB & 63;
  const char* Ab = (const char*)A;
  const char* Bb = (const char*)B;

#define STAGE(buf, kk) do { \
    gload16(Ab + ((size_t)(rowA0 + rA1) * lda + (kk)) * 2 + cA1, (char*)As[buf] + oA1); \
    gload16(Ab + ((size_t)(rowA0 + rA2) * lda + (kk)) * 2 + cA1, (char*)As[buf] + oA2); \
    gload16(Bb + ((size_t)(colB0 + rB)  * ldb + (kk)) * 2 + cB,  (char*)Bs[buf] + oB);  \
  } while (0)

  f32x4 acc[4][2] = {};

  // prologue: stage tiles 0 and 1 (depth-2)
  STAGE(0, kb0);
  if (nt > 1) STAGE(1, kb0 + 32);

  int cur = 0;
  for (int t = 0; t < nt; ++t) {
    // wait for tile t (issued at t-2 or prologue); keep tile t+1's 3 loads in flight
    if (t + 1 < nt) asm volatile("s_waitcnt vmcnt(3)" ::: "memory");
    else            asm volatile("s_waitcnt vmcnt(0)" ::: "memory");
    __builtin_amdgcn_s_barrier();            // tile t visible to all waves
    __builtin_amdgcn_sched_barrier(0);

    // stage tile t+2 into the buffer read at iter t-1 (safe past the barrier)
    if (t + 2 < nt) {
      int nxt = cur + 2; if (nxt >= 3) nxt -= 3;
      STAGE(nxt, kb0 + (t + 2) * 32);
    }

    s16x8 af[4], bv[2];
#pragma unroll
    for (int mt = 0; mt < 4; mt++)
      af[mt] = *(const s16x8*)&As[cur][(wm + mt * 16 + lr) * 32 + lg * 8];
#pragma unroll
    for (int nt2 = 0; nt2 < 2; nt2++)
      bv[nt2] = *(const s16x8*)&Bs[cur][(wn + nt2 * 16 + lr) * 32 + lg * 8];
    asm volatile("s_waitcnt lgkmcnt(0)" ::: "memory");
    __builtin_amdgcn_sched_barrier(0);
#pragma unroll
    for (int mt = 0; mt < 4; mt++)
#pragma unroll
      for (int nt2 = 0; nt2 < 2; nt2++)
        acc[mt][nt2] = __builtin_amdgcn_mfma_f32_16x16x32_bf16(af[mt], bv[nt2], acc[mt][nt2], 0, 0, 0);

    cur = (cur == 2) ? 0 : cur + 1;
  }
#undef STAGE

#pragma unroll
  for (int mt = 0; mt < 4; mt++) {
    const int rr = rowA0 + wm + mt * 16 + lg * 4;
#pragma unroll
    for (int nt2 = 0; nt2 < 2; nt2++) {
      const int cc = colB0 + wn + nt2 * 16 + lr;
      const float bvl = (cc < nbias) ? bias[cc] : 0.0f;
#pragma unroll
      for (int i = 0; i < 4; i++) {
        float v = acc[mt][nt2][i] + bvl;
        const int row = rr + i;
        if (MODE == 0) {
          ((bf_t*)outp)[(size_t)row * ldc + cc] = f2b(v);
        } else if (MODE == 2) {
          if (cc < nvalid)      ((bf_t*)outp)[(size_t)row * ldc + cc] = f2b(gelu_f(v));
          else if (cc < ldc)    ((bf_t*)outp)[(size_t)row * ldc + cc] = 0;
        } else { // MODE 3
          float* P = (float*)outp + (size_t)bz * ((size_t)S_LEN * ldc);
          P[(size_t)row * ldc + cc] = v;
        }
      }
    }
  }
}

// ---------------- split-K reduce: out = resid + bias + sum(partials) --------
__global__ __launch_bounds__(256) void reduce_kernel(
    const float* __restrict__ part, const float* __restrict__ bias,
    const float* __restrict__ resid, float* __restrict__ outp)
{
  int idx = blockIdx.x * 256 + threadIdx.x;   // float4 index over [2048][1152]
  if (idx >= S_LEN * HID / 4) return;
  float4 r = ((const float4*)resid)[idx];
  float4 bv = ((const float4*)bias)[idx % (HID / 4)];
  float sx = r.x + bv.x, sy = r.y + bv.y, sz = r.z + bv.z, sw = r.w + bv.w;
#pragma unroll
  for (int p = 0; p < 4; p++) {
    float4 v = ((const float4*)(part + (size_t)p * S_LEN * HID))[idx];
    sx += v.x; sy += v.y; sz += v.z; sw += v.w;
  }
  ((float4*)outp)[idx] = make_float4(sx, sy, sz, sw);
}

// ---------------- flash attention within segments ----------------
#define QSTR 104
#define VSTR 72
#define PSTR 72
__global__ __launch_bounds__(256, 2) void attn_kernel(
    const bf_t* __restrict__ qkv, const int* __restrict__ cu, int nseg,
    bf_t* __restrict__ outb)
{
  __shared__ __align__(16) bf_t Qs[64 * QSTR];
  __shared__ __align__(16) bf_t Ks[64 * QSTR];
  __shared__ __align__(16) bf_t VTs[80 * VSTR];
  __shared__ __align__(16) bf_t Pb[4][16 * PSTR];
  const int tid = threadIdx.x;
  const int l = tid & 63, w = tid >> 6;
  const int lr = l & 15, lg = l >> 4;
  const int h = blockIdx.y;
  const int qbase = blockIdx.x * 64;

  int kstart = 0, kend = S_LEN;
  for (int s2 = 0; s2 < nseg; s2++) {
    int a = cu[s2], b = cu[s2 + 1];
    if (qbase >= a && qbase < b) { kstart = a; kend = b; }
  }

  for (int i = tid; i < 64 * QSTR; i += 256)
    if ((i % QSTR) >= HD) { Qs[i] = 0; Ks[i] = 0; }
  for (int i = tid; i < 80 * VSTR; i += 256)
    if ((i / VSTR) >= HD) VTs[i] = 0;
  for (int c = tid; c < 576; c += 256) {
    int r = c / 9, j = c % 9;
    *(s16x8*)&Qs[r * QSTR + j * 8] =
        *(const s16x8*)&qkv[(size_t)(qbase + r) * LD3 + h * HD + j * 8];
  }
  __syncthreads();
  s16x8 qf[3];
#pragma unroll
  for (int ks = 0; ks < 3; ks++)
    qf[ks] = *(const s16x8*)&Qs[(w * 16 + lr) * QSTR + ks * 32 + lg * 8];

  float m_i[4], l_i[4];
  f32x4 Of[5] = {};
#pragma unroll
  for (int i = 0; i < 4; i++) { m_i[i] = -1e30f; l_i[i] = 0.0f; }

  for (int kb = kstart; kb < kend; kb += 64) {
    __syncthreads();
    for (int c = tid; c < 576; c += 256) {
      int r = c / 9, j = c % 9;
      int gr = kb + r; if (gr >= kend) gr = kend - 1;
      *(s16x8*)&Ks[r * QSTR + j * 8] =
          *(const s16x8*)&qkv[(size_t)gr * LD3 + HID + h * HD + j * 8];
    }
    for (int c = tid; c < 576; c += 256) {
      int r = c / 9, j = c % 9;
      int gr = kb + r; if (gr >= kend) gr = kend - 1;
      s16x8 v = *(const s16x8*)&qkv[(size_t)gr * LD3 + 2 * HID + h * HD + j * 8];
#pragma unroll
      for (int jj = 0; jj < 8; jj++) VTs[(j * 8 + jj) * VSTR + r] = v[jj];
    }
    __syncthreads();

    f32x4 sc[4] = {};
#pragma unroll
    for (int kc = 0; kc < 4; kc++) {
#pragma unroll
      for (int ks = 0; ks < 3; ks++) {
        s16x8 kf = *(const s16x8*)&Ks[(kc * 16 + lr) * QSTR + ks * 32 + lg * 8];
        sc[kc] = __builtin_amdgcn_mfma_f32_16x16x32_bf16(qf[ks], kf, sc[kc], 0, 0, 0);
      }
    }
#pragma unroll
    for (int kc = 0; kc < 4; kc++) {
      if ((kb + kc * 16 + lr) >= kend) {
#pragma unroll
        for (int i = 0; i < 4; i++) sc[kc][i] = -1e30f;
      }
    }
    float tmax[4], scl[4], rs[4];
#pragma unroll
    for (int i = 0; i < 4; i++) {
      float t = fmaxf(fmaxf(sc[0][i], sc[1][i]), fmaxf(sc[2][i], sc[3][i]));
#pragma unroll
      for (int d2 = 1; d2 < 16; d2 <<= 1) t = fmaxf(t, __shfl_xor(t, d2));
      tmax[i] = t;
    }
#pragma unroll
    for (int i = 0; i < 4; i++) {
      float mn = fmaxf(m_i[i], tmax[i]);
      scl[i] = __expf(m_i[i] - mn);
      m_i[i] = mn;
      rs[i] = 0.0f;
    }
#pragma unroll
    for (int kc = 0; kc < 4; kc++)
#pragma unroll
      for (int i = 0; i < 4; i++) {
        float p = __expf(sc[kc][i] - m_i[i]);
        sc[kc][i] = p;
        rs[i] += p;
      }
#pragma unroll
    for (int i = 0; i < 4; i++) {
#pragma unroll
      for (int d2 = 1; d2 < 16; d2 <<= 1) rs[i] += __shfl_xor(rs[i], d2);
      l_i[i] = l_i[i] * scl[i] + rs[i];
    }
#pragma unroll
    for (int nt = 0; nt < 5; nt++)
#pragma unroll
      for (int i = 0; i < 4; i++) Of[nt][i] *= scl[i];
#pragma unroll
    for (int kc = 0; kc < 4; kc++)
#pragma unroll
      for (int i = 0; i < 4; i++)
        Pb[w][(lg * 4 + i) * PSTR + kc * 16 + lr] = f2b(sc[kc][i]);
    __syncthreads();
    s16x8 pf[2];
#pragma unroll
    for (int k2 = 0; k2 < 2; k2++)
      pf[k2] = *(const s16x8*)&Pb[w][lr * PSTR + k2 * 32 + lg * 8];
#pragma unroll
    for (int nt = 0; nt < 5; nt++) {
#pragma unroll
      for (int k2 = 0; k2 < 2; k2++) {
        s16x8 vf = *(const s16x8*)&VTs[(nt * 16 + lr) * VSTR + k2 * 32 + lg * 8];
        Of[nt] = __builtin_amdgcn_mfma_f32_16x16x32_bf16(pf[k2], vf, Of[nt], 0, 0, 0);
      }
    }
  }
  float inv[4];
#pragma unroll
  for (int i = 0; i < 4; i++) inv[i] = 1.0f / l_i[i];
#pragma unroll
  for (int nt = 0; nt < 5; nt++) {
    int cc = nt * 16 + lr;
    if (cc < HD) {
#pragma unroll
      for (int i = 0; i < 4; i++) {
        int row = qbase + w * 16 + lg * 4 + i;
        outb[(size_t)row * HID + h * HD + cc] = f2b(Of[nt][i] * inv[i]);
      }
    }
  }
}

// ---------------- host orchestration ----------------
extern "C" void kernel_launch(void* const* d_in, const int* in_sizes, int n_in,
                              void* d_out, int out_size, void* d_ws, size_t ws_size,
                              hipStream_t stream) {
  const float* x     = (const float*)d_in[0];
  const int*   cu    = (const int*)d_in[1];
  const float* rotab = (const float*)d_in[2];
  const float* n1w   = (const float*)d_in[3];
  const float* n1b   = (const float*)d_in[4];
  const float* qkvw  = (const float*)d_in[5];
  const float* qkvb  = (const float*)d_in[6];
  const float* projw = (const float*)d_in[7];
  const float* projb = (const float*)d_in[8];
  const float* n2w   = (const float*)d_in[9];
  const float* n2b   = (const float*)d_in[10];
  const float* fc1w  = (const float*)d_in[11];
  const float* fc1b  = (const float*)d_in[12];
  const float* fc2w  = (const float*)d_in[13];
  const float* fc2b  = (const float*)d_in[14];
  float* out = (float*)d_out;
  char* ws = (char*)d_ws;

  size_t off = 0;
  float* xbuf = (float*)(ws + off); off += (size_t)S_LEN * HID * 4;        // 9.44 MB
  bf_t* hbf   = (bf_t*)(ws + off);  off += (size_t)S_LEN * HID * 2;        // 4.72 MB
  bf_t* qkvbf = (bf_t*)(ws + off);                                          // shared slot
  bf_t* ff1bf = (bf_t*)(ws + off);  off += (size_t)S_LEN * FFP * 2;        // 17.69 MB
  bf_t* attnbf= (bf_t*)(ws + off);  off += (size_t)S_LEN * HID * 2;        // 4.72 MB
  bf_t* wslot = (bf_t*)(ws + off);  off += (size_t)4352 * 1152 * 2;        // 10.03 MB
  float* ctab = (float*)(ws + off); off += (size_t)S_LEN * ROT * 4;
  float* stab = (float*)(ws + off); off += (size_t)S_LEN * ROT * 4;
  float* part = (float*)(ws + off); off += (size_t)4 * S_LEN * HID * 4;    // 37.75 MB

  hipMemcpyAsync(xbuf, x, (size_t)S_LEN * HID * 4, hipMemcpyDeviceToDevice, stream);
  costab_kernel<<<(S_LEN * ROT + 255) / 256, 256, 0, stream>>>(rotab, ctab, stab);

  const int nseg = in_sizes[1] - 1;
  const int RED_GRID = (S_LEN * HID / 4 + 255) / 256;

  for (int d = 0; d < 2; d++) {
    // LN1
    ln_kernel<<<S_LEN, 256, 0, stream>>>(xbuf, n1w + d * HID, n1b + d * HID, hbf);
    // QKV (grid 54x16 = 864 blocks)
    convw4_kernel<<<(LD3 * HID / 4 + 255) / 256, 256, 0, stream>>>(
        qkvw + (size_t)d * LD3 * HID, LD3, HID, wslot, HID);
    gemm_bt<0><<<dim3(LD3 / 64, 16), 256, 0, stream>>>(
        hbf, HID, wslot, HID, qkvb + (size_t)d * LD3, LD3, qkvbf, LD3, LD3, HID, HID);
    rotary_kernel<<<(S_LEN * HEADS * ROT + 255) / 256, 256, 0, stream>>>(qkvbf, ctab, stab);
    // attention
    attn_kernel<<<dim3(S_LEN / 64, HEADS), 256, 0, stream>>>(qkvbf, cu, nseg, attnbf);
    // proj: split-K x4 (K=1152 -> 288), grid 18x16x4 = 1152 blocks
    convw4_kernel<<<(HID * HID / 4 + 255) / 256, 256, 0, stream>>>(
        projw + (size_t)d * HID * HID, HID, HID, wslot, HID);
    gemm_bt<3><<<dim3(HID / 64, 16, 4), 256, 0, stream>>>(
        attnbf, HID, wslot, HID, nullptr, 0, part, HID, HID, HID, 288);
    reduce_kernel<<<RED_GRID, 256, 0, stream>>>(part, projb + (size_t)d * HID, xbuf, xbuf);
    // LN2
    ln_kernel<<<S_LEN, 256, 0, stream>>>(xbuf, n2w + d * HID, n2b + d * HID, hbf);
    // FC1 (+gelu) -> ff1 (grid 68x16 = 1088 blocks; cols [4304,4320) zeroed)
    convw4_kernel<<<(FF * HID / 4 + 255) / 256, 256, 0, stream>>>(
        fc1w + (size_t)d * FF * HID, FF, HID, wslot, HID);
    gemm_bt<2><<<dim3(4352 / 64, 16), 256, 0, stream>>>(
        hbf, HID, wslot, HID, fc1b + (size_t)d * FF, FF, ff1bf, FFP, FF, HID, HID);
    // FC2: split-K x4 (K=4320 -> 1088/1088/1088/1056), grid 18x16x4
    convw4_kernel<<<(HID * FFP / 4 + 255) / 256, 256, 0, stream>>>(
        fc2w + (size_t)d * HID * FF, HID, FF, wslot, FFP);
    gemm_bt<3><<<dim3(HID / 64, 16, 4), 256, 0, stream>>>(
        ff1bf, FFP, wslot, FFP, nullptr, 0, part, HID, HID, FFP, 1088);
    float* outp = (d == 1) ? out : xbuf;
    reduce_kernel<<<RED_GRID, 256, 0, stream>>>(part, fc2b + (size_t)d * HID, xbuf, outp);
  }
}

// Round 5
// 450.610 us; speedup vs baseline: 1.1918x; 1.1918x over previous
//
#include <hip/hip_runtime.h>

#define S_LEN 2048
#define HID   1152
#define HEADS 16
#define HD    72
#define ROT   36
#define LD3   3456   // 3*HID
#define FF    4304
#define FFP   4320   // FF padded to mult of 32

typedef short s16x8 __attribute__((ext_vector_type(8)));
typedef short s16x4 __attribute__((ext_vector_type(4)));
typedef float f32x4 __attribute__((ext_vector_type(4)));
typedef short bf_t;  // bf16 bit pattern

__device__ __forceinline__ short f2b(float f) {
  unsigned u = __float_as_uint(f);
  u += 0x7fffu + ((u >> 16) & 1u);   // RNE
  return (short)(u >> 16);
}
__device__ __forceinline__ float b2f(short h) {
  return __uint_as_float(((unsigned)(unsigned short)h) << 16);
}
__device__ __forceinline__ float gelu_f(float x) {
  float t = tanhf(0.7978845608028654f * (x + 0.044715f * x * x * x));
  return 0.5f * x * (1.0f + t);
}

typedef const __attribute__((address_space(1))) void* gas_p;
typedef __attribute__((address_space(3))) void* las_p;
__device__ __forceinline__ void gload16(const void* g, void* l) {
  __builtin_amdgcn_global_load_lds((gas_p)g, (las_p)l, 16, 0, 0);
}

// ---------------- weight convert f32 -> bf16, vectorized x4, k-zero-pad ------
__global__ __launch_bounds__(256) void convw4_kernel(
    const float* __restrict__ src, int N, int K,
    bf_t* __restrict__ dst, int Kpad)
{
  int idx = blockIdx.x * 256 + threadIdx.x;
  int kq = Kpad >> 2;
  if (idx >= N * kq) return;
  int n = idx / kq, k = (idx % kq) << 2;
  s16x4 o;
  if (k + 3 < K) {
    float4 v = *(const float4*)(src + (size_t)n * K + k);
    o[0] = f2b(v.x); o[1] = f2b(v.y); o[2] = f2b(v.z); o[3] = f2b(v.w);
  } else {
#pragma unroll
    for (int j = 0; j < 4; j++) {
      int kk = k + j;
      o[j] = (kk < K) ? f2b(src[(size_t)n * K + kk]) : (short)0;
    }
  }
  *(s16x4*)(dst + (size_t)n * Kpad + k) = o;
}

// ---------------- cos/sin table ----------------
__global__ __launch_bounds__(256) void costab_kernel(
    const float* __restrict__ rot, float* __restrict__ ct, float* __restrict__ st)
{
  int i = blockIdx.x * 256 + threadIdx.x;
  if (i < S_LEN * ROT) { float f = rot[i]; ct[i] = cosf(f); st[i] = sinf(f); }
}

// ---------------- layernorm: f32 in -> bf16 out ----------------
__global__ __launch_bounds__(256) void ln_kernel(
    const float* __restrict__ x, const float* __restrict__ wgt,
    const float* __restrict__ bia, bf_t* __restrict__ outb)
{
  const int row = blockIdx.x, tid = threadIdx.x;
  const float4* xr = (const float4*)(x + (size_t)row * HID);
  float4 a = xr[tid];
  float4 b2 = make_float4(0.f, 0.f, 0.f, 0.f);
  const bool has2 = tid < 32;
  if (has2) b2 = xr[256 + tid];
  float s = a.x + a.y + a.z + a.w + b2.x + b2.y + b2.z + b2.w;
  float q = a.x*a.x + a.y*a.y + a.z*a.z + a.w*a.w
          + b2.x*b2.x + b2.y*b2.y + b2.z*b2.z + b2.w*b2.w;
  for (int mk = 32; mk; mk >>= 1) { s += __shfl_xor(s, mk); q += __shfl_xor(q, mk); }
  __shared__ float red[16];
  if ((tid & 63) == 0) { red[tid >> 6] = s; red[8 + (tid >> 6)] = q; }
  __syncthreads();
  if (tid == 0) {
    red[4]  = red[0] + red[1] + red[2] + red[3];
    red[12] = red[8] + red[9] + red[10] + red[11];
  }
  __syncthreads();
  float mean = red[4] * (1.0f / HID);
  float var  = red[12] * (1.0f / HID) - mean * mean;
  float rstd = rsqrtf(var + 1e-6f);
  const float4* w4 = (const float4*)wgt;
  const float4* b4 = (const float4*)bia;
  s16x4* o4 = (s16x4*)(outb + (size_t)row * HID);
  {
    float4 wv = w4[tid], bv = b4[tid];
    s16x4 o;
    o[0] = f2b((a.x - mean) * rstd * wv.x + bv.x);
    o[1] = f2b((a.y - mean) * rstd * wv.y + bv.y);
    o[2] = f2b((a.z - mean) * rstd * wv.z + bv.z);
    o[3] = f2b((a.w - mean) * rstd * wv.w + bv.w);
    o4[tid] = o;
  }
  if (has2) {
    float4 wv = w4[256 + tid], bv = b4[256 + tid];
    s16x4 o;
    o[0] = f2b((b2.x - mean) * rstd * wv.x + bv.x);
    o[1] = f2b((b2.y - mean) * rstd * wv.y + bv.y);
    o[2] = f2b((b2.z - mean) * rstd * wv.z + bv.z);
    o[3] = f2b((b2.w - mean) * rstd * wv.w + bv.w);
    o4[256 + tid] = o;
  }
}

// ---------------- rotary in-place on qkv (bf16), q pre-scaled ----------------
__global__ __launch_bounds__(256) void rotary_kernel(
    bf_t* __restrict__ qkv, const float* __restrict__ ct, const float* __restrict__ st)
{
  int idx = blockIdx.x * 256 + threadIdx.x;
  if (idx >= S_LEN * HEADS * ROT) return;
  int t = idx / (HEADS * ROT);
  int r = idx % (HEADS * ROT);
  int h = r / ROT, dd = r % ROT;
  float c = ct[t * ROT + dd], s = st[t * ROT + dd];
  size_t base = (size_t)t * LD3 + h * HD + dd;
  float q1 = b2f(qkv[base]),        q2 = b2f(qkv[base + ROT]);
  float k1 = b2f(qkv[base + HID]),  k2 = b2f(qkv[base + HID + ROT]);
  const float scale = 0.11785113019775793f; // 1/sqrt(72)
  qkv[base]             = f2b((q1 * c - q2 * s) * scale);
  qkv[base + ROT]       = f2b((q2 * c + q1 * s) * scale);
  qkv[base + HID]       = f2b(k1 * c - k2 * s);
  qkv[base + HID + ROT] = f2b(k2 * c + k1 * s);
}

// ============ GEMM variant 1 (R2-exact): BM=128,BN=128, single-buffer =======
// Best for split-K N=1152 shapes (proj, fc2).
// MODE 3: out f32 partial = acc, at part + bz*S_LEN*ldc (split-K)
template<int MODE>
__global__ __launch_bounds__(256, 4) void gemm1(
    const bf_t* __restrict__ A, int lda,
    const bf_t* __restrict__ B, int ldb,
    const float* __restrict__ bias, int nbias,
    void* outp, int ldc, int nvalid, int K, int kchunk)
{
  __shared__ __align__(16) bf_t As[128 * 32];
  __shared__ __align__(16) bf_t Bs[128 * 32];
  const int tid = threadIdx.x;
  const int l = tid & 63, w = tid >> 6;
  const int lr = l & 15, lg = l >> 4;
  const int wm = (w >> 1) * 64, wn = (w & 1) * 64;

  unsigned gx = gridDim.x, gy = gridDim.y, gz = gridDim.z;
  unsigned nwg = gx * gy * gz;
  unsigned lin = (blockIdx.z * gy + blockIdx.y) * gx + blockIdx.x;
  if ((nwg & 7u) == 0u) {
    unsigned q = nwg >> 3;
    lin = (lin & 7u) * q + (lin >> 3);
  }
  const unsigned bz = lin / (gx * gy);
  const unsigned rem = lin % (gx * gy);
  const unsigned by = rem / gx, bx = rem % gx;

  const int rowA0 = by * 128, colB0 = bx * 128;
  const int kb0 = bz * kchunk;
  int kb1 = kb0 + kchunk; if (kb1 > K) kb1 = K;

  const int o1 = tid * 16, o2 = o1 + 4096;
  const int r1 = o1 >> 6, c1 = o1 & 63;
  const int r2 = o2 >> 6, c2 = o2 & 63;
  const char* Ab = (const char*)A;
  const char* Bb = (const char*)B;

  f32x4 acc[4][4] = {};

  for (int kb = kb0; kb < kb1; kb += 32) {
    gload16(Ab + ((size_t)(rowA0 + r1) * lda + kb) * 2 + c1, (char*)As + o1);
    gload16(Ab + ((size_t)(rowA0 + r2) * lda + kb) * 2 + c2, (char*)As + o2);
    gload16(Bb + ((size_t)(colB0 + r1) * ldb + kb) * 2 + c1, (char*)Bs + o1);
    gload16(Bb + ((size_t)(colB0 + r2) * ldb + kb) * 2 + c2, (char*)Bs + o2);
    asm volatile("s_waitcnt vmcnt(0)" ::: "memory");
    __syncthreads();
    s16x8 af[4], bv[4];
#pragma unroll
    for (int mt = 0; mt < 4; mt++) af[mt] = *(const s16x8*)&As[(wm + mt * 16 + lr) * 32 + lg * 8];
#pragma unroll
    for (int nt = 0; nt < 4; nt++) bv[nt] = *(const s16x8*)&Bs[(wn + nt * 16 + lr) * 32 + lg * 8];
#pragma unroll
    for (int mt = 0; mt < 4; mt++)
#pragma unroll
      for (int nt = 0; nt < 4; nt++)
        acc[mt][nt] = __builtin_amdgcn_mfma_f32_16x16x32_bf16(af[mt], bv[nt], acc[mt][nt], 0, 0, 0);
    __syncthreads();
  }

#pragma unroll
  for (int mt = 0; mt < 4; mt++) {
    const int rr = rowA0 + wm + mt * 16 + lg * 4;
#pragma unroll
    for (int nt = 0; nt < 4; nt++) {
      const int cc = colB0 + wn + nt * 16 + lr;
      const float bvl = (cc < nbias) ? bias[cc] : 0.0f;
#pragma unroll
      for (int i = 0; i < 4; i++) {
        float v = acc[mt][nt][i] + bvl;
        const int row = rr + i;
        if (MODE == 0) {
          ((bf_t*)outp)[(size_t)row * ldc + cc] = f2b(v);
        } else if (MODE == 2) {
          if (cc < nvalid)      ((bf_t*)outp)[(size_t)row * ldc + cc] = f2b(gelu_f(v));
          else if (cc < ldc)    ((bf_t*)outp)[(size_t)row * ldc + cc] = 0;
        } else { // MODE 3
          float* P = (float*)outp + (size_t)bz * ((size_t)S_LEN * ldc);
          P[(size_t)row * ldc + cc] = v;
        }
      }
    }
  }
}

// ============ GEMM variant 2 (R3-exact): BM=128,BN=64, 2-buf prefetch =======
// Best for large-N/small-K shapes (qkv, fc1).
template<int MODE>
__global__ __launch_bounds__(256, 4) void gemm2(
    const bf_t* __restrict__ A, int lda,
    const bf_t* __restrict__ B, int ldb,
    const float* __restrict__ bias, int nbias,
    void* outp, int ldc, int nvalid, int K, int kchunk)
{
  __shared__ __align__(16) bf_t As[2][128 * 32];
  __shared__ __align__(16) bf_t Bs[2][64 * 32];
  const int tid = threadIdx.x;
  const int l = tid & 63, w = tid >> 6;
  const int lr = l & 15, lg = l >> 4;
  const int wm = (w >> 1) * 64, wn = (w & 1) * 32;

  unsigned gx = gridDim.x, gy = gridDim.y, gz = gridDim.z;
  unsigned nwg = gx * gy * gz;
  unsigned lin = (blockIdx.z * gy + blockIdx.y) * gx + blockIdx.x;
  if ((nwg & 7u) == 0u) {
    unsigned q = nwg >> 3;
    lin = (lin & 7u) * q + (lin >> 3);
  }
  const unsigned bz = lin / (gx * gy);
  const unsigned rem = lin % (gx * gy);
  const unsigned by = rem / gx, bx = rem % gx;

  const int rowA0 = by * 128, colB0 = bx * 64;
  const int kb0 = bz * kchunk;
  int kb1 = kb0 + kchunk; if (kb1 > K) kb1 = K;

  const int oA1 = tid * 16, oA2 = oA1 + 4096;
  const int rA1 = oA1 >> 6, cA1 = oA1 & 63;
  const int rA2 = rA1 + 64;
  const int oB = tid * 16;
  const int rB = oB >> 6, cB = oB & 63;
  const char* Ab = (const char*)A;
  const char* Bb = (const char*)B;

#define STAGE(buf, kk) do { \
    gload16(Ab + ((size_t)(rowA0 + rA1) * lda + (kk)) * 2 + cA1, (char*)As[buf] + oA1); \
    gload16(Ab + ((size_t)(rowA0 + rA2) * lda + (kk)) * 2 + cA1, (char*)As[buf] + oA2); \
    gload16(Bb + ((size_t)(colB0 + rB)  * ldb + (kk)) * 2 + cB,  (char*)Bs[buf] + oB);  \
  } while (0)

  f32x4 acc[4][2] = {};

  STAGE(0, kb0);
  asm volatile("s_waitcnt vmcnt(0)" ::: "memory");
  __builtin_amdgcn_s_barrier();
  __builtin_amdgcn_sched_barrier(0);

  int cur = 0;
  for (int kb = kb0; kb < kb1; kb += 32) {
    if (kb + 32 < kb1) STAGE(cur ^ 1, kb + 32);
    s16x8 af[4], bv[2];
#pragma unroll
    for (int mt = 0; mt < 4; mt++)
      af[mt] = *(const s16x8*)&As[cur][(wm + mt * 16 + lr) * 32 + lg * 8];
#pragma unroll
    for (int nt = 0; nt < 2; nt++)
      bv[nt] = *(const s16x8*)&Bs[cur][(wn + nt * 16 + lr) * 32 + lg * 8];
    asm volatile("s_waitcnt lgkmcnt(0)" ::: "memory");
    __builtin_amdgcn_sched_barrier(0);
#pragma unroll
    for (int mt = 0; mt < 4; mt++)
#pragma unroll
      for (int nt = 0; nt < 2; nt++)
        acc[mt][nt] = __builtin_amdgcn_mfma_f32_16x16x32_bf16(af[mt], bv[nt], acc[mt][nt], 0, 0, 0);
    asm volatile("s_waitcnt vmcnt(0)" ::: "memory");
    __builtin_amdgcn_s_barrier();
    __builtin_amdgcn_sched_barrier(0);
    cur ^= 1;
  }
#undef STAGE

#pragma unroll
  for (int mt = 0; mt < 4; mt++) {
    const int rr = rowA0 + wm + mt * 16 + lg * 4;
#pragma unroll
    for (int nt = 0; nt < 2; nt++) {
      const int cc = colB0 + wn + nt * 16 + lr;
      const float bvl = (cc < nbias) ? bias[cc] : 0.0f;
#pragma unroll
      for (int i = 0; i < 4; i++) {
        float v = acc[mt][nt][i] + bvl;
        const int row = rr + i;
        if (MODE == 0) {
          ((bf_t*)outp)[(size_t)row * ldc + cc] = f2b(v);
        } else if (MODE == 2) {
          if (cc < nvalid)      ((bf_t*)outp)[(size_t)row * ldc + cc] = f2b(gelu_f(v));
          else if (cc < ldc)    ((bf_t*)outp)[(size_t)row * ldc + cc] = 0;
        } else { // MODE 3
          float* P = (float*)outp + (size_t)bz * ((size_t)S_LEN * ldc);
          P[(size_t)row * ldc + cc] = v;
        }
      }
    }
  }
}

// ---------------- split-K reduce: out = resid + bias + sum(partials) --------
__global__ __launch_bounds__(256) void reduce_kernel(
    const float* __restrict__ part, const float* __restrict__ bias,
    const float* __restrict__ resid, float* __restrict__ outp)
{
  int idx = blockIdx.x * 256 + threadIdx.x;   // float4 index over [2048][1152]
  if (idx >= S_LEN * HID / 4) return;
  float4 r = ((const float4*)resid)[idx];
  float4 bv = ((const float4*)bias)[idx % (HID / 4)];
  float sx = r.x + bv.x, sy = r.y + bv.y, sz = r.z + bv.z, sw = r.w + bv.w;
#pragma unroll
  for (int p = 0; p < 4; p++) {
    float4 v = ((const float4*)(part + (size_t)p * S_LEN * HID))[idx];
    sx += v.x; sy += v.y; sz += v.z; sw += v.w;
  }
  ((float4*)outp)[idx] = make_float4(sx, sy, sz, sw);
}

// ---------------- flash attention within segments ----------------
#define QSTR 104
#define VSTR 72
#define PSTR 72
__global__ __launch_bounds__(256, 2) void attn_kernel(
    const bf_t* __restrict__ qkv, const int* __restrict__ cu, int nseg,
    bf_t* __restrict__ outb)
{
  __shared__ __align__(16) bf_t Qs[64 * QSTR];
  __shared__ __align__(16) bf_t Ks[64 * QSTR];
  __shared__ __align__(16) bf_t VTs[80 * VSTR];
  __shared__ __align__(16) bf_t Pb[4][16 * PSTR];
  const int tid = threadIdx.x;
  const int l = tid & 63, w = tid >> 6;
  const int lr = l & 15, lg = l >> 4;
  const int h = blockIdx.y;
  const int qbase = blockIdx.x * 64;

  int kstart = 0, kend = S_LEN;
  for (int s2 = 0; s2 < nseg; s2++) {
    int a = cu[s2], b = cu[s2 + 1];
    if (qbase >= a && qbase < b) { kstart = a; kend = b; }
  }

  for (int i = tid; i < 64 * QSTR; i += 256)
    if ((i % QSTR) >= HD) { Qs[i] = 0; Ks[i] = 0; }
  for (int i = tid; i < 80 * VSTR; i += 256)
    if ((i / VSTR) >= HD) VTs[i] = 0;
  for (int c = tid; c < 576; c += 256) {
    int r = c / 9, j = c % 9;
    *(s16x8*)&Qs[r * QSTR + j * 8] =
        *(const s16x8*)&qkv[(size_t)(qbase + r) * LD3 + h * HD + j * 8];
  }
  __syncthreads();
  s16x8 qf[3];
#pragma unroll
  for (int ks = 0; ks < 3; ks++)
    qf[ks] = *(const s16x8*)&Qs[(w * 16 + lr) * QSTR + ks * 32 + lg * 8];

  float m_i[4], l_i[4];
  f32x4 Of[5] = {};
#pragma unroll
  for (int i = 0; i < 4; i++) { m_i[i] = -1e30f; l_i[i] = 0.0f; }

  for (int kb = kstart; kb < kend; kb += 64) {
    __syncthreads();
    for (int c = tid; c < 576; c += 256) {
      int r = c / 9, j = c % 9;
      int gr = kb + r; if (gr >= kend) gr = kend - 1;
      *(s16x8*)&Ks[r * QSTR + j * 8] =
          *(const s16x8*)&qkv[(size_t)gr * LD3 + HID + h * HD + j * 8];
    }
    for (int c = tid; c < 576; c += 256) {
      int r = c / 9, j = c % 9;
      int gr = kb + r; if (gr >= kend) gr = kend - 1;
      s16x8 v = *(const s16x8*)&qkv[(size_t)gr * LD3 + 2 * HID + h * HD + j * 8];
#pragma unroll
      for (int jj = 0; jj < 8; jj++) VTs[(j * 8 + jj) * VSTR + r] = v[jj];
    }
    __syncthreads();

    f32x4 sc[4] = {};
#pragma unroll
    for (int kc = 0; kc < 4; kc++) {
#pragma unroll
      for (int ks = 0; ks < 3; ks++) {
        s16x8 kf = *(const s16x8*)&Ks[(kc * 16 + lr) * QSTR + ks * 32 + lg * 8];
        sc[kc] = __builtin_amdgcn_mfma_f32_16x16x32_bf16(qf[ks], kf, sc[kc], 0, 0, 0);
      }
    }
#pragma unroll
    for (int kc = 0; kc < 4; kc++) {
      if ((kb + kc * 16 + lr) >= kend) {
#pragma unroll
        for (int i = 0; i < 4; i++) sc[kc][i] = -1e30f;
      }
    }
    float tmax[4], scl[4], rs[4];
#pragma unroll
    for (int i = 0; i < 4; i++) {
      float t = fmaxf(fmaxf(sc[0][i], sc[1][i]), fmaxf(sc[2][i], sc[3][i]));
#pragma unroll
      for (int d2 = 1; d2 < 16; d2 <<= 1) t = fmaxf(t, __shfl_xor(t, d2));
      tmax[i] = t;
    }
#pragma unroll
    for (int i = 0; i < 4; i++) {
      float mn = fmaxf(m_i[i], tmax[i]);
      scl[i] = __expf(m_i[i] - mn);
      m_i[i] = mn;
      rs[i] = 0.0f;
    }
#pragma unroll
    for (int kc = 0; kc < 4; kc++)
#pragma unroll
      for (int i = 0; i < 4; i++) {
        float p = __expf(sc[kc][i] - m_i[i]);
        sc[kc][i] = p;
        rs[i] += p;
      }
#pragma unroll
    for (int i = 0; i < 4; i++) {
#pragma unroll
      for (int d2 = 1; d2 < 16; d2 <<= 1) rs[i] += __shfl_xor(rs[i], d2);
      l_i[i] = l_i[i] * scl[i] + rs[i];
    }
#pragma unroll
    for (int nt = 0; nt < 5; nt++)
#pragma unroll
      for (int i = 0; i < 4; i++) Of[nt][i] *= scl[i];
#pragma unroll
    for (int kc = 0; kc < 4; kc++)
#pragma unroll
      for (int i = 0; i < 4; i++)
        Pb[w][(lg * 4 + i) * PSTR + kc * 16 + lr] = f2b(sc[kc][i]);
    __syncthreads();
    s16x8 pf[2];
#pragma unroll
    for (int k2 = 0; k2 < 2; k2++)
      pf[k2] = *(const s16x8*)&Pb[w][lr * PSTR + k2 * 32 + lg * 8];
#pragma unroll
    for (int nt = 0; nt < 5; nt++) {
#pragma unroll
      for (int k2 = 0; k2 < 2; k2++) {
        s16x8 vf = *(const s16x8*)&VTs[(nt * 16 + lr) * VSTR + k2 * 32 + lg * 8];
        Of[nt] = __builtin_amdgcn_mfma_f32_16x16x32_bf16(pf[k2], vf, Of[nt], 0, 0, 0);
      }
    }
  }
  float inv[4];
#pragma unroll
  for (int i = 0; i < 4; i++) inv[i] = 1.0f / l_i[i];
#pragma unroll
  for (int nt = 0; nt < 5; nt++) {
    int cc = nt * 16 + lr;
    if (cc < HD) {
#pragma unroll
      for (int i = 0; i < 4; i++) {
        int row = qbase + w * 16 + lg * 4 + i;
        outb[(size_t)row * HID + h * HD + cc] = f2b(Of[nt][i] * inv[i]);
      }
    }
  }
}

// ---------------- host orchestration ----------------
extern "C" void kernel_launch(void* const* d_in, const int* in_sizes, int n_in,
                              void* d_out, int out_size, void* d_ws, size_t ws_size,
                              hipStream_t stream) {
  const float* x     = (const float*)d_in[0];
  const int*   cu    = (const int*)d_in[1];
  const float* rotab = (const float*)d_in[2];
  const float* n1w   = (const float*)d_in[3];
  const float* n1b   = (const float*)d_in[4];
  const float* qkvw  = (const float*)d_in[5];
  const float* qkvb  = (const float*)d_in[6];
  const float* projw = (const float*)d_in[7];
  const float* projb = (const float*)d_in[8];
  const float* n2w   = (const float*)d_in[9];
  const float* n2b   = (const float*)d_in[10];
  const float* fc1w  = (const float*)d_in[11];
  const float* fc1b  = (const float*)d_in[12];
  const float* fc2w  = (const float*)d_in[13];
  const float* fc2b  = (const float*)d_in[14];
  float* out = (float*)d_out;
  char* ws = (char*)d_ws;

  size_t off = 0;
  float* xbuf = (float*)(ws + off); off += (size_t)S_LEN * HID * 4;        // 9.44 MB
  bf_t* hbf   = (bf_t*)(ws + off);  off += (size_t)S_LEN * HID * 2;        // 4.72 MB
  bf_t* qkvbf = (bf_t*)(ws + off);                                          // shared slot
  bf_t* ff1bf = (bf_t*)(ws + off);  off += (size_t)S_LEN * FFP * 2;        // 17.69 MB
  bf_t* attnbf= (bf_t*)(ws + off);  off += (size_t)S_LEN * HID * 2;        // 4.72 MB
  bf_t* wslot = (bf_t*)(ws + off);  off += (size_t)4352 * 1152 * 2;        // 10.03 MB
  float* ctab = (float*)(ws + off); off += (size_t)S_LEN * ROT * 4;
  float* stab = (float*)(ws + off); off += (size_t)S_LEN * ROT * 4;
  float* part = (float*)(ws + off); off += (size_t)4 * S_LEN * HID * 4;    // 37.75 MB

  costab_kernel<<<(S_LEN * ROT + 255) / 256, 256, 0, stream>>>(rotab, ctab, stab);

  const int nseg = in_sizes[1] - 1;
  const int RED_GRID = (S_LEN * HID / 4 + 255) / 256;

  for (int d = 0; d < 2; d++) {
    const float* xin = (d == 0) ? x : xbuf;   // residual spine source
    // LN1
    ln_kernel<<<S_LEN, 256, 0, stream>>>(xin, n1w + d * HID, n1b + d * HID, hbf);
    // QKV: gemm2 (BN=64, 2-buf), grid 54x16 = 864 blocks
    convw4_kernel<<<(LD3 * HID / 4 + 255) / 256, 256, 0, stream>>>(
        qkvw + (size_t)d * LD3 * HID, LD3, HID, wslot, HID);
    gemm2<0><<<dim3(LD3 / 64, 16), 256, 0, stream>>>(
        hbf, HID, wslot, HID, qkvb + (size_t)d * LD3, LD3, qkvbf, LD3, LD3, HID, HID);
    rotary_kernel<<<(S_LEN * HEADS * ROT + 255) / 256, 256, 0, stream>>>(qkvbf, ctab, stab);
    // attention
    attn_kernel<<<dim3(S_LEN / 64, HEADS), 256, 0, stream>>>(qkvbf, cu, nseg, attnbf);
    // proj: gemm1 (BN=128, 1-buf) split-K x4 (K=1152 -> 288), grid 9x16x4 = 576
    convw4_kernel<<<(HID * HID / 4 + 255) / 256, 256, 0, stream>>>(
        projw + (size_t)d * HID * HID, HID, HID, wslot, HID);
    gemm1<3><<<dim3(HID / 128, 16, 4), 256, 0, stream>>>(
        attnbf, HID, wslot, HID, nullptr, 0, part, HID, HID, HID, 288);
    reduce_kernel<<<RED_GRID, 256, 0, stream>>>(part, projb + (size_t)d * HID, xin, xbuf);
    // LN2
    ln_kernel<<<S_LEN, 256, 0, stream>>>(xbuf, n2w + d * HID, n2b + d * HID, hbf);
    // FC1 (+gelu): gemm2, grid 68x16 = 1088 blocks
    convw4_kernel<<<(FF * HID / 4 + 255) / 256, 256, 0, stream>>>(
        fc1w + (size_t)d * FF * HID, FF, HID, wslot, HID);
    gemm2<2><<<dim3(4352 / 64, 16), 256, 0, stream>>>(
        hbf, HID, wslot, HID, fc1b + (size_t)d * FF, FF, ff1bf, FFP, FF, HID, HID);
    // FC2: gemm1 split-K x4 (K=4320 -> 1088/1088/1088/1056), grid 9x16x4 = 576
    convw4_kernel<<<(HID * FFP / 4 + 255) / 256, 256, 0, stream>>>(
        fc2w + (size_t)d * HID * FF, HID, FF, wslot, FFP);
    gemm1<3><<<dim3(HID / 128, 16, 4), 256, 0, stream>>>(
        ff1bf, FFP, wslot, FFP, nullptr, 0, part, HID, HID, FFP, 1088);
    float* outp = (d == 1) ? out : xbuf;
    reduce_kernel<<<RED_GRID, 256, 0, stream>>>(part, fc2b + (size_t)d * HID, xbuf, outp);
  }
}